// Round 7
// baseline (3260.606 us; speedup 1.0000x reference)
//
#include <hip/hip_runtime.h>
#include <cstdint>

#define B_    64
#define T_    2700
#define HID_  128
#define PRE_  32
#define VMAX_ 256
#define NG_   16   // xg batch groups of 4 (layout unchanged)
#define NB_   4    // batches per group
#define NBLK_ 8    // k_scan blocks (2 groups each)
#define TCH_  27   // k_xg t-chunks
#define TSZ_  100  // t per chunk

typedef _Float16 half2_t __attribute__((ext_vector_type(2)));
typedef _Float16 half4_t __attribute__((ext_vector_type(4)));
typedef _Float16 half8_t __attribute__((ext_vector_type(8)));
typedef float    f32x4_t __attribute__((ext_vector_type(4)));
union H8u { half8_t v; half2_t p[4]; };

#define MFMA32(A, Bv, C) __builtin_amdgcn_mfma_f32_16x16x32_f16((A), (Bv), (C), 0, 0, 0)

#if __has_builtin(__builtin_amdgcn_fdot2)
__device__ __forceinline__ float FDOT2(half2_t a, half2_t b, float c) {
    return __builtin_amdgcn_fdot2(a, b, c, false);
}
#else
__device__ __forceinline__ float FDOT2(half2_t a, half2_t b, float c) {
    return c + (float)a[0] * (float)b[0] + (float)a[1] * (float)b[1];
}
#endif

__device__ __forceinline__ half2_t mk2(float a, float b) {
    half2_t r; r[0] = (_Float16)a; r[1] = (_Float16)b; return r;
}
__device__ __forceinline__ float fast_sigmoid(float x) {
    float t = __builtin_amdgcn_exp2f(-1.4426950408889634f * x);
    return __builtin_amdgcn_rcpf(1.0f + t);
}
__device__ __forceinline__ float fast_tanh(float x) {
    float t = __builtin_amdgcn_exp2f(2.885390081777927f * x);
    return 1.0f - 2.0f * __builtin_amdgcn_rcpf(t + 1.0f);
}
// pull the (sel)-th accumulator element from source lane (addr>>2)
__device__ __forceinline__ float pick_reg(f32x4_t v, int addr, int sel) {
    float t0 = __int_as_float(__builtin_amdgcn_ds_bpermute(addr, __float_as_int(v[0])));
    float t1 = __int_as_float(__builtin_amdgcn_ds_bpermute(addr, __float_as_int(v[1])));
    float t2 = __int_as_float(__builtin_amdgcn_ds_bpermute(addr, __float_as_int(v[2])));
    float t3 = __int_as_float(__builtin_amdgcn_ds_bpermute(addr, __float_as_int(v[3])));
    float a = (sel & 1) ? t1 : t0;
    float b = (sel & 1) ? t3 : t2;
    return (sel & 2) ? b : a;
}

// ---------------------------------------------------------------------------
// Kernel 1: neighborhood assembly + pre = sigmoid(inp @ W_pre.T + b_pre).
// fp16 output packed for K=32 B-fragments: pre16[g][t][hi(4)][cs(4)][j(8)].
// ---------------------------------------------------------------------------
__global__ __launch_bounds__(256) void k_pre(const float* __restrict__ x,
                                             const float* __restrict__ W_pre,
                                             const float* __restrict__ b_pre,
                                             _Float16* __restrict__ pre16) {
    int tid  = blockIdx.x * 256 + threadIdx.x;   // < 64*900*3*32
    int i    = tid & 31;          // k index into PRE
    int rest = tid >> 5;          // (b*900+p)*3 + c
    int c    = rest % 3;
    int r2   = rest / 3;          // b*900 + p
    int p    = r2 % 900;
    int b    = r2 / 900;
    int r    = p / 30;
    int cc   = p - r * 30;
    const float* xb = x + b * 3072 + r * 32 + cc;  // x[b][ch][r][cc] at xb[ch*1024]
    float f0 = xb[0],    f1  = xb[1024], f2  = xb[2048];   // tl
    float f3 = xb[1],    f4  = xb[1025], f5  = xb[2049];   // tc
    float f6 = xb[2],    f7  = xb[1026], f8  = xb[2050];   // tr
    float f9 = xb[32],   f10 = xb[1056], f11 = xb[2080];   // lf
    float ct0 = xb[33],  ct1 = xb[1057];                   // ct[0..1]
    float f12 = (c >= 1) ? ct0 : -1.0f;
    float f13 = (c >= 2) ? ct1 : -1.0f;
    const float* w = W_pre + i * 14;
    float d = b_pre[i];
    d += f0*w[0]  + f1*w[1]  + f2*w[2]  + f3*w[3]  + f4*w[4]  + f5*w[5]  + f6*w[6]
       + f7*w[7]  + f8*w[8]  + f9*w[9]  + f10*w[10] + f11*w[11] + f12*w[12] + f13*w[13];

    int t  = p * 3 + c;           // time index
    int g  = b >> 2;              // batch group
    int cs = b & 3;               // batch slot within group
    size_t base = ((size_t)g * T_ + t) * 128;     // 128 halves per (g,t)
    int idx = ((i >> 3) << 5) | (cs << 3) | (i & 7);   // [hi][cs][j]
    pre16[base + idx] = (_Float16)fast_sigmoid(d);
}

// ---------------------------------------------------------------------------
// Kernel 1b: xg[g][t][tid] = {xr', xz', xn', 0} fp16 (8B/thread), where
// u3 = (tid>>6)*16 + ((tid&63)>>2), c4 = tid&3 — matches k_scan's lane
// ownership exactly, so k_scan loads its values with one coalesced 8B load.
// xr' = pre.Wr + b_ih_r + b_hh_r; xz' likewise; xn' = pre.Wn + b_ih_n.
// ---------------------------------------------------------------------------
__global__ __launch_bounds__(512) void k_xg(const float* __restrict__ W_ih,
                                            const float* __restrict__ b_ih,
                                            const float* __restrict__ b_hh,
                                            const _Float16* __restrict__ pre16,
                                            _Float16* __restrict__ xg16) {
    const int tid = threadIdx.x;
    const int g   = blockIdx.x / TCH_;
    const int tc  = blockIdx.x % TCH_;
    const int u3  = (tid >> 6) * 16 + ((tid & 63) >> 2);
    const int c4  = tid & 3;

    half2_t wr[16], wz[16], wn[16];
    const float* Wr = W_ih + (size_t)u3 * PRE_;
    const float* Wz = W_ih + (size_t)(128 + u3) * PRE_;
    const float* Wn = W_ih + (size_t)(256 + u3) * PRE_;
#pragma unroll
    for (int k2 = 0; k2 < 16; ++k2) {
        wr[k2] = mk2(Wr[2*k2], Wr[2*k2 + 1]);
        wz[k2] = mk2(Wz[2*k2], Wz[2*k2 + 1]);
        wn[k2] = mk2(Wn[2*k2], Wn[2*k2 + 1]);
    }
    const float br = b_ih[u3] + b_hh[u3];
    const float bz = b_ih[128 + u3] + b_hh[128 + u3];
    const float bn = b_ih[256 + u3];

    const char* preg = (const char*)pre16 + ((size_t)g * T_ + (size_t)tc * TSZ_) * 256 + c4 * 16;
    H8u pc0, pc1, pc2, pc3;
    pc0.v = *(const half8_t*)(preg +   0);
    pc1.v = *(const half8_t*)(preg +  64);
    pc2.v = *(const half8_t*)(preg + 128);
    pc3.v = *(const half8_t*)(preg + 192);

    for (int tt = 0; tt < TSZ_; ++tt) {
        const int ttn = (tt + 1 < TSZ_) ? tt + 1 : tt;
        H8u n0, n1, n2, n3;
        n0.v = *(const half8_t*)(preg + (size_t)ttn * 256 +   0);
        n1.v = *(const half8_t*)(preg + (size_t)ttn * 256 +  64);
        n2.v = *(const half8_t*)(preg + (size_t)ttn * 256 + 128);
        n3.v = *(const half8_t*)(preg + (size_t)ttn * 256 + 192);

        float ar = br, az = bz, an = bn;
#pragma unroll
        for (int j2 = 0; j2 < 4; ++j2) { ar = FDOT2(wr[ 0+j2], pc0.p[j2], ar); az = FDOT2(wz[ 0+j2], pc0.p[j2], az); an = FDOT2(wn[ 0+j2], pc0.p[j2], an); }
#pragma unroll
        for (int j2 = 0; j2 < 4; ++j2) { ar = FDOT2(wr[ 4+j2], pc1.p[j2], ar); az = FDOT2(wz[ 4+j2], pc1.p[j2], az); an = FDOT2(wn[ 4+j2], pc1.p[j2], an); }
#pragma unroll
        for (int j2 = 0; j2 < 4; ++j2) { ar = FDOT2(wr[ 8+j2], pc2.p[j2], ar); az = FDOT2(wz[ 8+j2], pc2.p[j2], az); an = FDOT2(wn[ 8+j2], pc2.p[j2], an); }
#pragma unroll
        for (int j2 = 0; j2 < 4; ++j2) { ar = FDOT2(wr[12+j2], pc3.p[j2], ar); az = FDOT2(wz[12+j2], pc3.p[j2], az); an = FDOT2(wn[12+j2], pc3.p[j2], an); }

        const size_t t = (size_t)tc * TSZ_ + tt;
        half4_t o;
        o[0] = (_Float16)ar; o[1] = (_Float16)az; o[2] = (_Float16)an; o[3] = (_Float16)0.f;
        *(half4_t*)((char*)xg16 + (((size_t)g * T_ + t) * 512 + tid) * 8) = o;
        pc0 = n0; pc1 = n1; pc2 = n2; pc3 = n3;
    }
}

// ---------------------------------------------------------------------------
// Kernel 1c: W_post -> fp16, row-major [256][128]. Written into the dead
// pre16 region (runs after k_xg).
// ---------------------------------------------------------------------------
__global__ __launch_bounds__(256) void k_wcvt(const float* __restrict__ W_post,
                                              _Float16* __restrict__ w16) {
    int idx = blockIdx.x * 256 + threadIdx.x;   // 32768
    w16[idx] = (_Float16)W_post[idx];
}

// ---------------------------------------------------------------------------
// Kernel 2: persistent GRU scan v7 — two-group software pipeline.
// 8 blocks x 512 thr; block bg owns batches 8bg..8bg+7 = group A (xg group
// 2bg) + group B (xg group 2bg+1). Each barrier interval overlaps MFMA of
// one group with the EPILOGUE of the other (D of the other group sits in
// registers from the previous interval), so the MFMA pipe, LDS pipe and
// VALU/trans pipes run concurrently instead of phase-locked serial.
// Two intervals per step; totals (MFMA count, epilogue work, xg/hs traffic)
// unchanged. hbuf single-buffered per group (write-after-read protected by
// the interval barrier + lgkmcnt drain). Arithmetic order per chain is
// identical to round 6 -> same absmax.
// ---------------------------------------------------------------------------
__global__ __launch_bounds__(512, 1) void k_scan(const float* __restrict__ W_hh,
                                                 const float* __restrict__ b_hh,
                                                 const _Float16* __restrict__ xg16,
                                                 _Float16* __restrict__ hs16) {
    // h state, B-frag layout per group: [grp][kc][hi][c][j], u = kc*32+8*hi+j
    __shared__ __align__(16) _Float16 hbuf[2][4][4][4][8];   // 2 KB

    const int tid  = threadIdx.x;
    const int bg   = blockIdx.x;        // 0..7
    const int w    = tid >> 6;
    const int lane = tid & 63;
    const int lo   = lane & 15;
    const int hi   = lane >> 4;
    const int c4   = lane & 3;
    const int row  = w * 16 + lo;

    half8_t Ar[4], Az[4], Ahn[4];
#pragma unroll
    for (int kc = 0; kc < 4; ++kc) {
        half8_t ar, az, an;
#pragma unroll
        for (int j = 0; j < 8; ++j) {
            int k = kc * 32 + hi * 8 + j;
            ar[j] = (_Float16)W_hh[row * HID_ + k];
            az[j] = (_Float16)W_hh[(128 + row) * HID_ + k];
            an[j] = (_Float16)W_hh[(256 + row) * HID_ + k];
        }
        Ar[kc] = ar; Az[kc] = az; Ahn[kc] = an;
    }

    const int u3 = w * 16 + (lane >> 2);
    const float bhn = b_hh[256 + u3];
    const int srcaddr = ((((lane >> 4) << 4) | c4) << 2);
    const int sel     = (lane >> 2) & 3;

    const char* xgpA = (const char*)xg16 + ((size_t)(2 * bg)     * T_ * 512 + tid) * 8;
    const char* xgpB = (const char*)xg16 + ((size_t)(2 * bg + 1) * T_ * 512 + tid) * 8;
    _Float16* hsbA = hs16 + (size_t)(8 * bg + c4)     * T_ * HID_ + u3;
    _Float16* hsbB = hs16 + (size_t)(8 * bg + 4 + c4) * T_ * HID_ + u3;

    const int kc_w = u3 >> 5;
    const int hi_w = (u3 >> 3) & 3;
    const int j_w  = u3 & 7;

    ((uint32_t*)hbuf)[tid] = 0u;   // zero-init both groups (512 dwords)

    half4_t xhA = *(const half4_t*)(xgpA);
    half4_t xhB = *(const half4_t*)(xgpB);
    float hpA = 0.0f, hpB = 0.0f;

    const f32x4_t Z4 = {0.f, 0.f, 0.f, 0.f};
    f32x4_t rA = Z4, zA = Z4, nA = Z4;          // D_A (valid: h_A(0)=0 -> D=0)
    f32x4_t rB = Z4, zB = Z4, nB = Z4;
    __syncthreads();

    for (int t = 0; t < T_; ++t) {
        const int tn = (t + 1 < T_) ? (t + 1) : t;
        half4_t xAn = *(const half4_t*)(xgpA + (size_t)tn * 4096);
        half4_t xBn = *(const half4_t*)(xgpB + (size_t)tn * 4096);

        // ---- interval 1: MFMA over h_B(t) ; epilogue for group A ----
        {
            half8_t b0 = *(const half8_t*)&hbuf[1][0][hi][c4][0];
            half8_t b1 = *(const half8_t*)&hbuf[1][1][hi][c4][0];
            half8_t b2 = *(const half8_t*)&hbuf[1][2][hi][c4][0];
            half8_t b3 = *(const half8_t*)&hbuf[1][3][hi][c4][0];
            rB = Z4; zB = Z4; nB = Z4;
            rB = MFMA32(Ar[0],  b0, rB);
            zB = MFMA32(Az[0],  b0, zB);
            nB = MFMA32(Ahn[0], b0, nB);
            rB = MFMA32(Ar[1],  b1, rB);
            zB = MFMA32(Az[1],  b1, zB);
            nB = MFMA32(Ahn[1], b1, nB);
            rB = MFMA32(Ar[2],  b2, rB);
            zB = MFMA32(Az[2],  b2, zB);
            nB = MFMA32(Ahn[2], b2, nB);
            rB = MFMA32(Ar[3],  b3, rB);
            zB = MFMA32(Az[3],  b3, zB);
            nB = MFMA32(Ahn[3], b3, nB);

            float srr = pick_reg(rA, srcaddr, sel) + (float)xhA[0];
            float szz = pick_reg(zA, srcaddr, sel) + (float)xhA[1];
            float shn = pick_reg(nA, srcaddr, sel) + bhn;
            float rg   = fast_sigmoid(srr);
            float zg   = fast_sigmoid(szz);
            float ng   = fast_tanh((float)xhA[2] + rg * shn);
            float hnew = ng + zg * (hpA - ng);
            hpA = hnew;
            _Float16 h16 = (_Float16)hnew;
            hbuf[0][kc_w][hi_w][c4][j_w] = h16;
            hsbA[(size_t)t * HID_] = h16;

            asm volatile("s_waitcnt lgkmcnt(0)" ::: "memory");
            __builtin_amdgcn_s_barrier();
        }

        // ---- interval 2: MFMA over h_A(t+1) ; epilogue for group B ----
        {
            half8_t a0 = *(const half8_t*)&hbuf[0][0][hi][c4][0];
            half8_t a1 = *(const half8_t*)&hbuf[0][1][hi][c4][0];
            half8_t a2 = *(const half8_t*)&hbuf[0][2][hi][c4][0];
            half8_t a3 = *(const half8_t*)&hbuf[0][3][hi][c4][0];
            rA = Z4; zA = Z4; nA = Z4;
            rA = MFMA32(Ar[0],  a0, rA);
            zA = MFMA32(Az[0],  a0, zA);
            nA = MFMA32(Ahn[0], a0, nA);
            rA = MFMA32(Ar[1],  a1, rA);
            zA = MFMA32(Az[1],  a1, zA);
            nA = MFMA32(Ahn[1], a1, nA);
            rA = MFMA32(Ar[2],  a2, rA);
            zA = MFMA32(Az[2],  a2, zA);
            nA = MFMA32(Ahn[2], a2, nA);
            rA = MFMA32(Ar[3],  a3, rA);
            zA = MFMA32(Az[3],  a3, zA);
            nA = MFMA32(Ahn[3], a3, nA);

            float srr = pick_reg(rB, srcaddr, sel) + (float)xhB[0];
            float szz = pick_reg(zB, srcaddr, sel) + (float)xhB[1];
            float shn = pick_reg(nB, srcaddr, sel) + bhn;
            float rg   = fast_sigmoid(srr);
            float zg   = fast_sigmoid(szz);
            float ng   = fast_tanh((float)xhB[2] + rg * shn);
            float hnew = ng + zg * (hpB - ng);
            hpB = hnew;
            _Float16 h16 = (_Float16)hnew;
            hbuf[1][kc_w][hi_w][c4][j_w] = h16;
            hsbB[(size_t)t * HID_] = h16;

            asm volatile("s_waitcnt lgkmcnt(0)" ::: "memory");
            __builtin_amdgcn_s_barrier();
        }

        xhA = xAn; xhB = xBn;
    }
}

// ---------------------------------------------------------------------------
// Kernel 3: out = hs @ W_post.T + b_post as MFMA GEMM, no LDS, no barriers.
// (round-5 proven: non-scan time 693 -> 378 us, absmax unchanged)
// ---------------------------------------------------------------------------
__global__ __launch_bounds__(512, 2) void k_post(const _Float16* __restrict__ w16,
                                                 const float* __restrict__ b_post,
                                                 const _Float16* __restrict__ hs,
                                                 float* __restrict__ out) {
    const int tid  = threadIdx.x;
    const int blk  = blockIdx.x;       // 64*3*32
    const int i    = blk & 31;
    const int rest = blk >> 5;
    const int ch   = rest % 3;
    const int b    = rest / 3;
    float* outb = out + ((size_t)(b * 3 + ch) * 1024 + i * 32) * VMAX_;

    const float4 z4 = {0.f, 0.f, 0.f, 0.f};
    if (i == 0 || i == 31) {           // full 32x256 zero tile
        float4* o4 = (float4*)outb;    // 2048 float4
#pragma unroll
        for (int k = 0; k < 4; ++k) o4[k * 512 + tid] = z4;
        return;
    }
    // zero rows jc=0 and jc=31 (64 float4 each)
    if (tid < 64)       ((float4*)outb)[tid] = z4;
    else if (tid < 128) ((float4*)(outb + 31 * VMAX_))[tid - 64] = z4;

    const int wv   = tid >> 6;
    const int lane = tid & 63;
    const int lo   = lane & 15;
    const int hi   = lane >> 4;
    const int t0   = (i - 1) * 90 + ch;    // t = t0 + 3*m, m = jc-1 in [0,30)
    const _Float16* hsb = hs + (size_t)b * T_ * HID_;

    half8_t Af[2][4], Bf[2][4];
#pragma unroll
    for (int mt = 0; mt < 2; ++mt) {
        int m = mt * 16 + lo; if (m > 29) m = 29;          // clamp pad rows
        const _Float16* ap = hsb + (size_t)(t0 + 3 * m) * HID_ + hi * 8;
#pragma unroll
        for (int kc = 0; kc < 4; ++kc) Af[mt][kc] = *(const half8_t*)(ap + kc * 32);
    }
    const int vb = wv * 32;
#pragma unroll
    for (int nt = 0; nt < 2; ++nt) {
        const _Float16* bp = w16 + (size_t)(vb + nt * 16 + lo) * HID_ + hi * 8;
#pragma unroll
        for (int kc = 0; kc < 4; ++kc) Bf[nt][kc] = *(const half8_t*)(bp + kc * 32);
    }
    const float bp0 = b_post[vb + lo];
    const float bp1 = b_post[vb + 16 + lo];

    f32x4_t a00 = {0.f,0.f,0.f,0.f}, a01 = a00, a10 = a00, a11 = a00;
#pragma unroll
    for (int kc = 0; kc < 4; ++kc) {
        a00 = MFMA32(Af[0][kc], Bf[0][kc], a00);
        a01 = MFMA32(Af[0][kc], Bf[1][kc], a01);
        a10 = MFMA32(Af[1][kc], Bf[0][kc], a10);
        a11 = MFMA32(Af[1][kc], Bf[1][kc], a11);
    }

#pragma unroll
    for (int q = 0; q < 4; ++q) {
        {   // mt = 0: m = 4*hi+q in [0,16) always valid
            float* orow = outb + (size_t)(1 + 4 * hi + q) * VMAX_;
            orow[vb + lo]      = a00[q] + bp0;
            orow[vb + 16 + lo] = a01[q] + bp1;
        }
        if (4 * hi + q <= 13) {   // mt = 1: m = 16+4*hi+q must be <= 29
            float* orow = outb + (size_t)(17 + 4 * hi + q) * VMAX_;
            orow[vb + lo]      = a10[q] + bp0;
            orow[vb + 16 + lo] = a11[q] + bp1;
        }
    }
}

extern "C" void kernel_launch(void* const* d_in, const int* in_sizes, int n_in,
                              void* d_out, int out_size, void* d_ws, size_t ws_size,
                              hipStream_t stream) {
    const float* x      = (const float*)d_in[0];
    const float* W_pre  = (const float*)d_in[1];
    const float* b_pre  = (const float*)d_in[2];
    const float* W_ih   = (const float*)d_in[3];
    const float* b_ih   = (const float*)d_in[4];
    const float* W_hh   = (const float*)d_in[5];
    const float* b_hh   = (const float*)d_in[6];
    const float* W_post = (const float*)d_in[7];
    const float* b_post = (const float*)d_in[8];
    float* out = (float*)d_out;

    // ws layout: pre16 (11.06 MB, reused as w16 after k_xg) | xg (176.9 MB) |
    //            hs16 (44.2 MB). Total 232.3 MB (rounds 3-6 ran this layout).
    const size_t pre_bytes = (size_t)NG_ * T_ * 256;
    const size_t xg_bytes  = (size_t)NG_ * T_ * 512 * 8;
    _Float16* pre16 = (_Float16*)d_ws;
    _Float16* w16   = (_Float16*)d_ws;                    // overwrites pre16 after k_xg
    _Float16* xg    = (_Float16*)((char*)d_ws + pre_bytes);
    _Float16* hs16  = (_Float16*)((char*)d_ws + pre_bytes + xg_bytes);

    k_pre <<<21600, 256, 0, stream>>>(x, W_pre, b_pre, pre16);
    k_xg  <<<NG_ * TCH_, 512, 0, stream>>>(W_ih, b_ih, b_hh, pre16, xg);
    k_wcvt<<<128, 256, 0, stream>>>(W_post, w16);
    k_scan<<<NBLK_, 512, 0, stream>>>(W_hh, b_hh, xg, hs16);
    k_post<<<6144, 512, 0, stream>>>(w16, b_post, hs16, out);
}

// Round 8
// 2051.176 us; speedup vs baseline: 1.5896x; 1.5896x over previous
//
#include <hip/hip_runtime.h>
#include <cstdint>

#define B_    64
#define T_    2700
#define HID_  128
#define PRE_  32
#define VMAX_ 256
#define NG_   16   // pre16/k_xg batch groups of 4 (pre16 layout unchanged)
#define NB_   4
#define NG4_  4    // k_scan blocks: 4 blocks x 16 chains
#define TCH_  27   // k_xg t-chunks
#define TSZ_  100  // t per chunk

typedef _Float16 half2_t __attribute__((ext_vector_type(2)));
typedef _Float16 half4_t __attribute__((ext_vector_type(4)));
typedef _Float16 half8_t __attribute__((ext_vector_type(8)));
typedef float    f32x4_t __attribute__((ext_vector_type(4)));
union H8u { half8_t v; half2_t p[4]; };

#define MFMA32(A, Bv, C) __builtin_amdgcn_mfma_f32_16x16x32_f16((A), (Bv), (C), 0, 0, 0)

#if __has_builtin(__builtin_amdgcn_fdot2)
__device__ __forceinline__ float FDOT2(half2_t a, half2_t b, float c) {
    return __builtin_amdgcn_fdot2(a, b, c, false);
}
#else
__device__ __forceinline__ float FDOT2(half2_t a, half2_t b, float c) {
    return c + (float)a[0] * (float)b[0] + (float)a[1] * (float)b[1];
}
#endif

__device__ __forceinline__ half2_t mk2(float a, float b) {
    half2_t r; r[0] = (_Float16)a; r[1] = (_Float16)b; return r;
}
__device__ __forceinline__ float fast_sigmoid(float x) {
    float t = __builtin_amdgcn_exp2f(-1.4426950408889634f * x);
    return __builtin_amdgcn_rcpf(1.0f + t);
}
__device__ __forceinline__ float fast_tanh(float x) {
    float t = __builtin_amdgcn_exp2f(2.885390081777927f * x);
    return 1.0f - 2.0f * __builtin_amdgcn_rcpf(t + 1.0f);
}

// ---------------------------------------------------------------------------
// Kernel 1: neighborhood assembly + pre = sigmoid(inp @ W_pre.T + b_pre).
// fp16 output packed for K=32 B-fragments: pre16[g][t][hi(4)][cs(4)][j(8)].
// (unchanged)
// ---------------------------------------------------------------------------
__global__ __launch_bounds__(256) void k_pre(const float* __restrict__ x,
                                             const float* __restrict__ W_pre,
                                             const float* __restrict__ b_pre,
                                             _Float16* __restrict__ pre16) {
    int tid  = blockIdx.x * 256 + threadIdx.x;   // < 64*900*3*32
    int i    = tid & 31;          // k index into PRE
    int rest = tid >> 5;          // (b*900+p)*3 + c
    int c    = rest % 3;
    int r2   = rest / 3;          // b*900 + p
    int p    = r2 % 900;
    int b    = r2 / 900;
    int r    = p / 30;
    int cc   = p - r * 30;
    const float* xb = x + b * 3072 + r * 32 + cc;  // x[b][ch][r][cc] at xb[ch*1024]
    float f0 = xb[0],    f1  = xb[1024], f2  = xb[2048];   // tl
    float f3 = xb[1],    f4  = xb[1025], f5  = xb[2049];   // tc
    float f6 = xb[2],    f7  = xb[1026], f8  = xb[2050];   // tr
    float f9 = xb[32],   f10 = xb[1056], f11 = xb[2080];   // lf
    float ct0 = xb[33],  ct1 = xb[1057];                   // ct[0..1]
    float f12 = (c >= 1) ? ct0 : -1.0f;
    float f13 = (c >= 2) ? ct1 : -1.0f;
    const float* w = W_pre + i * 14;
    float d = b_pre[i];
    d += f0*w[0]  + f1*w[1]  + f2*w[2]  + f3*w[3]  + f4*w[4]  + f5*w[5]  + f6*w[6]
       + f7*w[7]  + f8*w[8]  + f9*w[9]  + f10*w[10] + f11*w[11] + f12*w[12] + f13*w[13];

    int t  = p * 3 + c;           // time index
    int g  = b >> 2;              // batch group
    int cs = b & 3;               // batch slot within group
    size_t base = ((size_t)g * T_ + t) * 128;     // 128 halves per (g,t)
    int idx = ((i >> 3) << 5) | (cs << 3) | (i & 7);   // [hi][cs][j]
    pre16[base + idx] = (_Float16)fast_sigmoid(d);
}

// ---------------------------------------------------------------------------
// Kernel 1b: xg precompute. Same math as rounds 5/6 (biases prefolded), new
// OUTPUT layout for the 16-chain scan: for scan-thread tid2 = w*64+hi_c*16+col
// (col = chain, hi_c = row-quad), cell q (u = w*16+4*hi_c+q):
//   byte addr = ((g4*T + t)*512 + tid2)*32 + q*8  -> {xr',xz',xn',0} half4.
// A scan lane then reads its 4 cells with two coalesced b128 loads.
// ---------------------------------------------------------------------------
__global__ __launch_bounds__(512) void k_xg(const float* __restrict__ W_ih,
                                            const float* __restrict__ b_ih,
                                            const float* __restrict__ b_hh,
                                            const _Float16* __restrict__ pre16,
                                            _Float16* __restrict__ xg16) {
    const int tid = threadIdx.x;
    const int g   = blockIdx.x / TCH_;
    const int tc  = blockIdx.x % TCH_;
    const int u3  = (tid >> 6) * 16 + ((tid & 63) >> 2);
    const int c4  = tid & 3;

    half2_t wr[16], wz[16], wn[16];
    const float* Wr = W_ih + (size_t)u3 * PRE_;
    const float* Wz = W_ih + (size_t)(128 + u3) * PRE_;
    const float* Wn = W_ih + (size_t)(256 + u3) * PRE_;
#pragma unroll
    for (int k2 = 0; k2 < 16; ++k2) {
        wr[k2] = mk2(Wr[2*k2], Wr[2*k2 + 1]);
        wz[k2] = mk2(Wz[2*k2], Wz[2*k2 + 1]);
        wn[k2] = mk2(Wn[2*k2], Wn[2*k2 + 1]);
    }
    const float br = b_ih[u3] + b_hh[u3];
    const float bz = b_ih[128 + u3] + b_hh[128 + u3];
    const float bn = b_ih[256 + u3];

    // scatter target (constant per thread)
    const int bb   = g * 4 + c4;          // batch
    const int g4   = bb >> 4;
    const int col  = bb & 15;
    const int w_   = u3 >> 4;
    const int rw   = u3 & 15;
    const int tid2 = w_ * 64 + (rw >> 2) * 16 + col;
    const int qo   = (rw & 3) * 8;        // byte offset of this cell's half4
    char* outp = (char*)xg16 + ((size_t)g4 * T_ * 512 + tid2) * 32 + qo;

    const char* preg = (const char*)pre16 + ((size_t)g * T_ + (size_t)tc * TSZ_) * 256 + c4 * 16;
    H8u pc0, pc1, pc2, pc3;
    pc0.v = *(const half8_t*)(preg +   0);
    pc1.v = *(const half8_t*)(preg +  64);
    pc2.v = *(const half8_t*)(preg + 128);
    pc3.v = *(const half8_t*)(preg + 192);

    for (int tt = 0; tt < TSZ_; ++tt) {
        const int ttn = (tt + 1 < TSZ_) ? tt + 1 : tt;
        H8u n0, n1, n2, n3;
        n0.v = *(const half8_t*)(preg + (size_t)ttn * 256 +   0);
        n1.v = *(const half8_t*)(preg + (size_t)ttn * 256 +  64);
        n2.v = *(const half8_t*)(preg + (size_t)ttn * 256 + 128);
        n3.v = *(const half8_t*)(preg + (size_t)ttn * 256 + 192);

        float ar = br, az = bz, an = bn;
#pragma unroll
        for (int j2 = 0; j2 < 4; ++j2) { ar = FDOT2(wr[ 0+j2], pc0.p[j2], ar); az = FDOT2(wz[ 0+j2], pc0.p[j2], az); an = FDOT2(wn[ 0+j2], pc0.p[j2], an); }
#pragma unroll
        for (int j2 = 0; j2 < 4; ++j2) { ar = FDOT2(wr[ 4+j2], pc1.p[j2], ar); az = FDOT2(wz[ 4+j2], pc1.p[j2], az); an = FDOT2(wn[ 4+j2], pc1.p[j2], an); }
#pragma unroll
        for (int j2 = 0; j2 < 4; ++j2) { ar = FDOT2(wr[ 8+j2], pc2.p[j2], ar); az = FDOT2(wz[ 8+j2], pc2.p[j2], az); an = FDOT2(wn[ 8+j2], pc2.p[j2], an); }
#pragma unroll
        for (int j2 = 0; j2 < 4; ++j2) { ar = FDOT2(wr[12+j2], pc3.p[j2], ar); az = FDOT2(wz[12+j2], pc3.p[j2], az); an = FDOT2(wn[12+j2], pc3.p[j2], an); }

        const size_t t = (size_t)tc * TSZ_ + tt;
        half4_t o;
        o[0] = (_Float16)ar; o[1] = (_Float16)az; o[2] = (_Float16)an; o[3] = (_Float16)0.f;
        *(half4_t*)(outp + t * 16384) = o;
        pc0 = n0; pc1 = n1; pc2 = n2; pc3 = n3;
    }
}

// ---------------------------------------------------------------------------
// Kernel 1c: W_post -> fp16, row-major [256][128]. Written into the dead
// pre16 region (runs after k_xg).
// ---------------------------------------------------------------------------
__global__ __launch_bounds__(256) void k_wcvt(const float* __restrict__ W_post,
                                              _Float16* __restrict__ w16) {
    int idx = blockIdx.x * 256 + threadIdx.x;   // 32768
    w16[idx] = (_Float16)W_post[idx];
}

// ---------------------------------------------------------------------------
// Kernel 2: persistent GRU scan v8 — 16 chains per block fill ALL 16 MFMA
// B-columns. 4 blocks x 512 thr. Same 12 MFMA/wave/step now serve 16 chains
// (4x the chain throughput per MFMA vs rounds 3-6). D layout (col=lane&15 =
// chain, row=4*hi+q; proven by k_post r5 + direct epilogue r4): every lane
// holds r/z/n for 4 gate-rows of its OWN chain in registers -> dense direct
// epilogue on all 64 lanes, ZERO bpermute, zero mux. h-exchange: 8KB
// double-buffered hbuf[kc][hi_k][chain(16)][j] (k-slot convention k =
// 32kc+8hi+j on both operands, proven r2-r6); read 4x b128 contiguous,
// write 1x ds_write_b64 per lane. xg: two coalesced b128 loads per lane
// (layout from k_xg above). ONE lgkmcnt(0)+s_barrier per step; global
// stores/loads stay in flight across it. Per-cell arithmetic identical to
// round 6 -> same absmax.
// ---------------------------------------------------------------------------
__global__ __launch_bounds__(512, 1) void k_scan(const float* __restrict__ W_hh,
                                                 const float* __restrict__ b_hh,
                                                 const _Float16* __restrict__ xg16,
                                                 _Float16* __restrict__ hs16) {
    __shared__ __align__(16) _Float16 hbuf[2][4][4][16][8];   // 8 KB

    const int tid  = threadIdx.x;
    const int g4   = blockIdx.x;        // 0..3
    const int w    = tid >> 6;
    const int lane = tid & 63;
    const int lo   = lane & 15;         // chain column (and A-row selector)
    const int hi   = lane >> 4;         // k-slot group / row-quad
    const int row  = w * 16 + lo;       // A-operand gate row

    // ---- weight A-fragments, slot j -> k = 32*kc + 8*hi + j ----
    half8_t Ar[4], Az[4], Ahn[4];
#pragma unroll
    for (int kc = 0; kc < 4; ++kc) {
        half8_t ar, az, an;
#pragma unroll
        for (int j = 0; j < 8; ++j) {
            int k = kc * 32 + hi * 8 + j;
            ar[j] = (_Float16)W_hh[row * HID_ + k];
            az[j] = (_Float16)W_hh[(128 + row) * HID_ + k];
            an[j] = (_Float16)W_hh[(256 + row) * HID_ + k];
        }
        Ar[kc] = ar; Az[kc] = az; Ahn[kc] = an;
    }

    // ---- this lane's 4 epilogue cells: chain lo, rows u0..u0+3 ----
    const int u0 = w * 16 + 4 * hi;
    const f32x4_t bhn4 = *(const f32x4_t*)(b_hh + 256 + u0);

    const char* xgp = (const char*)xg16 + ((size_t)g4 * T_ * 512 + tid) * 32;
    _Float16* hsb = hs16 + (size_t)(g4 * 16 + lo) * T_ * HID_ + u0;

    // h write slot: u0 -> kc_w = u0>>5, hi_w = (u0>>3)&3, j_w = u0&7 (4-aligned)
    const int kc_w = w >> 1;
    const int hi_w = (2 * w + (hi >> 1)) & 3;
    const int j_w  = 4 * (hi & 1);

    // zero-init both buffers: 8 KB = 2048 dwords
#pragma unroll
    for (int zz = 0; zz < 4; ++zz) ((uint32_t*)hbuf)[zz * 512 + tid] = 0u;

    half8_t x0 = *(const half8_t*)(xgp);
    half8_t x1 = *(const half8_t*)(xgp + 16);
    f32x4_t hp = {0.f, 0.f, 0.f, 0.f};
    __syncthreads();

    for (int t = 0; t < T_; ++t) {
        const size_t on = (size_t)((t + 1 < T_) ? t + 1 : t) * 16384;
        half8_t x0n = *(const half8_t*)(xgp + on);
        half8_t x1n = *(const half8_t*)(xgp + on + 16);

        const int rb = t & 1;
        half8_t hB0 = *(const half8_t*)&hbuf[rb][0][hi][lo][0];
        half8_t hB1 = *(const half8_t*)&hbuf[rb][1][hi][lo][0];
        half8_t hB2 = *(const half8_t*)&hbuf[rb][2][hi][lo][0];
        half8_t hB3 = *(const half8_t*)&hbuf[rb][3][hi][lo][0];

        const f32x4_t Z4 = {0.f, 0.f, 0.f, 0.f};
        f32x4_t r = Z4, z = Z4, n = Z4;
        r = MFMA32(Ar[0],  hB0, r);
        z = MFMA32(Az[0],  hB0, z);
        n = MFMA32(Ahn[0], hB0, n);
        r = MFMA32(Ar[1],  hB1, r);
        z = MFMA32(Az[1],  hB1, z);
        n = MFMA32(Ahn[1], hB1, n);
        r = MFMA32(Ar[2],  hB2, r);
        z = MFMA32(Az[2],  hB2, z);
        n = MFMA32(Ahn[2], hB2, n);
        r = MFMA32(Ar[3],  hB3, r);
        z = MFMA32(Az[3],  hB3, z);
        n = MFMA32(Ahn[3], hB3, n);

        half4_t hq;
#pragma unroll
        for (int q = 0; q < 4; ++q) {
            half8_t xv = (q < 2) ? x0 : x1;
            const int o = (q & 1) * 4;
            float rg = fast_sigmoid(r[q] + (float)xv[o]);
            float zg = fast_sigmoid(z[q] + (float)xv[o + 1]);
            float ng = fast_tanh((float)xv[o + 2] + rg * (n[q] + bhn4[q]));
            float hv = ng + zg * (hp[q] - ng);
            hp[q] = hv;
            hq[q] = (_Float16)hv;
        }
        *(half4_t*)&hbuf[rb ^ 1][kc_w][hi_w][lo][j_w] = hq;
        *(half4_t*)(hsb + (size_t)t * HID_) = hq;

        x0 = x0n; x1 = x1n;

        // LDS-only barrier: hbuf write visible; vmem stays in flight.
        asm volatile("s_waitcnt lgkmcnt(0)" ::: "memory");
        __builtin_amdgcn_s_barrier();
    }
}

// ---------------------------------------------------------------------------
// Kernel 3: out = hs @ W_post.T + b_post as MFMA GEMM, no LDS, no barriers.
// (round-5 proven; unchanged)
// ---------------------------------------------------------------------------
__global__ __launch_bounds__(512, 2) void k_post(const _Float16* __restrict__ w16,
                                                 const float* __restrict__ b_post,
                                                 const _Float16* __restrict__ hs,
                                                 float* __restrict__ out) {
    const int tid  = threadIdx.x;
    const int blk  = blockIdx.x;       // 64*3*32
    const int i    = blk & 31;
    const int rest = blk >> 5;
    const int ch   = rest % 3;
    const int b    = rest / 3;
    float* outb = out + ((size_t)(b * 3 + ch) * 1024 + i * 32) * VMAX_;

    const float4 z4 = {0.f, 0.f, 0.f, 0.f};
    if (i == 0 || i == 31) {           // full 32x256 zero tile
        float4* o4 = (float4*)outb;    // 2048 float4
#pragma unroll
        for (int k = 0; k < 4; ++k) o4[k * 512 + tid] = z4;
        return;
    }
    // zero rows jc=0 and jc=31 (64 float4 each)
    if (tid < 64)       ((float4*)outb)[tid] = z4;
    else if (tid < 128) ((float4*)(outb + 31 * VMAX_))[tid - 64] = z4;

    const int wv   = tid >> 6;
    const int lane = tid & 63;
    const int lo   = lane & 15;
    const int hi   = lane >> 4;
    const int t0   = (i - 1) * 90 + ch;    // t = t0 + 3*m, m = jc-1 in [0,30)
    const _Float16* hsb = hs + (size_t)b * T_ * HID_;

    half8_t Af[2][4], Bf[2][4];
#pragma unroll
    for (int mt = 0; mt < 2; ++mt) {
        int m = mt * 16 + lo; if (m > 29) m = 29;          // clamp pad rows
        const _Float16* ap = hsb + (size_t)(t0 + 3 * m) * HID_ + hi * 8;
#pragma unroll
        for (int kc = 0; kc < 4; ++kc) Af[mt][kc] = *(const half8_t*)(ap + kc * 32);
    }
    const int vb = wv * 32;
#pragma unroll
    for (int nt = 0; nt < 2; ++nt) {
        const _Float16* bp = w16 + (size_t)(vb + nt * 16 + lo) * HID_ + hi * 8;
#pragma unroll
        for (int kc = 0; kc < 4; ++kc) Bf[nt][kc] = *(const half8_t*)(bp + kc * 32);
    }
    const float bp0 = b_post[vb + lo];
    const float bp1 = b_post[vb + 16 + lo];

    f32x4_t a00 = {0.f,0.f,0.f,0.f}, a01 = a00, a10 = a00, a11 = a00;
#pragma unroll
    for (int kc = 0; kc < 4; ++kc) {
        a00 = MFMA32(Af[0][kc], Bf[0][kc], a00);
        a01 = MFMA32(Af[0][kc], Bf[1][kc], a01);
        a10 = MFMA32(Af[1][kc], Bf[0][kc], a10);
        a11 = MFMA32(Af[1][kc], Bf[1][kc], a11);
    }

#pragma unroll
    for (int q = 0; q < 4; ++q) {
        {   // mt = 0: m = 4*hi+q in [0,16) always valid
            float* orow = outb + (size_t)(1 + 4 * hi + q) * VMAX_;
            orow[vb + lo]      = a00[q] + bp0;
            orow[vb + 16 + lo] = a01[q] + bp1;
        }
        if (4 * hi + q <= 13) {   // mt = 1: m = 16+4*hi+q must be <= 29
            float* orow = outb + (size_t)(17 + 4 * hi + q) * VMAX_;
            orow[vb + lo]      = a10[q] + bp0;
            orow[vb + 16 + lo] = a11[q] + bp1;
        }
    }
}

extern "C" void kernel_launch(void* const* d_in, const int* in_sizes, int n_in,
                              void* d_out, int out_size, void* d_ws, size_t ws_size,
                              hipStream_t stream) {
    const float* x      = (const float*)d_in[0];
    const float* W_pre  = (const float*)d_in[1];
    const float* b_pre  = (const float*)d_in[2];
    const float* W_ih   = (const float*)d_in[3];
    const float* b_ih   = (const float*)d_in[4];
    const float* W_hh   = (const float*)d_in[5];
    const float* b_hh   = (const float*)d_in[6];
    const float* W_post = (const float*)d_in[7];
    const float* b_post = (const float*)d_in[8];
    float* out = (float*)d_out;

    // ws layout: pre16 (11.06 MB, reused as w16 after k_xg) | xg (176.9 MB) |
    //            hs16 (44.2 MB). Total 232.3 MB (rounds 3-7 ran this size).
    const size_t pre_bytes = (size_t)NG_ * T_ * 256;
    const size_t xg_bytes  = (size_t)NG4_ * T_ * 512 * 32;   // == 176.9 MB
    _Float16* pre16 = (_Float16*)d_ws;
    _Float16* w16   = (_Float16*)d_ws;                    // overwrites pre16 after k_xg
    _Float16* xg    = (_Float16*)((char*)d_ws + pre_bytes);
    _Float16* hs16  = (_Float16*)((char*)d_ws + pre_bytes + xg_bytes);

    k_pre <<<21600, 256, 0, stream>>>(x, W_pre, b_pre, pre16);
    k_xg  <<<NG_ * TCH_, 512, 0, stream>>>(W_ih, b_ih, b_hh, pre16, xg);
    k_wcvt<<<128, 256, 0, stream>>>(W_post, w16);
    k_scan<<<NG4_, 512, 0, stream>>>(W_hh, b_hh, xg, hs16);
    k_post<<<6144, 512, 0, stream>>>(w16, b_post, hs16, out);
}